// Round 1
// baseline (2576.446 us; speedup 1.0000x reference)
//
#include <hip/hip_runtime.h>
#include <hip/hip_bf16.h>

constexpr int D  = 128;
constexpr int H  = 8;
constexpr int DH = 16;

// ---------- helpers: order-preserving float<->uint for atomicMax ----------
__device__ inline unsigned int fkey(float f) {
  unsigned int u = __float_as_uint(f);
  return (u & 0x80000000u) ? ~u : (u | 0x80000000u);
}
__device__ inline float fdec(unsigned int k) {
  unsigned int u = (k & 0x80000000u) ? (k ^ 0x80000000u) : ~k;
  return __uint_as_float(u);
}

// ---------- FiLM: gb[0:128]=gamma, gb[128:256]=beta ----------
__global__ void k_film(const float* __restrict__ gc, const float* __restrict__ fw,
                       const float* __restrict__ fb, float* __restrict__ gb, int C) {
  int j = threadIdx.x;  // 256 threads
  float acc = fb[j];
  for (int c = 0; c < C; ++c) acc += gc[c] * fw[c * 256 + j];
  gb[j] = acc;
}

// ---------- init: h_agg=0, asum=0, amax_key=0 (== -inf) ----------
__global__ void k_init(float* __restrict__ hagg, float* __restrict__ asum,
                       unsigned int* __restrict__ amax, int N) {
  int i = blockIdx.x * blockDim.x + threadIdx.x;
  if (i < N * D) hagg[i] = 0.f;
  if (i < N * H) { asum[i] = 0.f; amax[i] = 0u; }
}

// ---------- per-node: k = x@Wk[t]; q = x@Wq[t]; v = x@Wv[t];
//            qt[h,d] = (rel_pri[h]/4) * sum_o rel_att[h,d,o]*q[h,o]
//            mt[h,o] = sum_d rel_msg[h,d,o]*v[h,d] ----------
__global__ void k_proj(const float* __restrict__ x, const int* __restrict__ ntype,
                       const float* __restrict__ Wk, const float* __restrict__ Wq,
                       const float* __restrict__ Wv, const float* __restrict__ ra_,
                       const float* __restrict__ rm_, const float* __restrict__ rp,
                       float* __restrict__ ok, float* __restrict__ oqt,
                       float* __restrict__ omt, int N) {
  int n = blockIdx.x;
  int j = threadIdx.x;  // 0..127
  __shared__ float xs[D], qs[D], vs[D];
  xs[j] = x[(size_t)n * D + j];
  __syncthreads();
  int t = ntype[n];
  const float* wk = Wk + (size_t)t * (D * D) + j;
  const float* wq = Wq + (size_t)t * (D * D) + j;
  const float* wv = Wv + (size_t)t * (D * D) + j;
  float ak = 0.f, aq = 0.f, av = 0.f;
#pragma unroll 8
  for (int d = 0; d < D; ++d) {
    float xv = xs[d];
    ak += xv * wk[d * D];
    aq += xv * wq[d * D];
    av += xv * wv[d * D];
  }
  ok[(size_t)n * D + j] = ak;
  qs[j] = aq;
  vs[j] = av;
  __syncthreads();
  int h = j >> 4, o = j & 15;
  const float* ra = ra_ + h * 256 + o * 16;  // rel_att[h, d=o, z]
  const float* rm = rm_ + h * 256 + o;       // rel_msg[h, z, o=o]
  float qt = 0.f, mt = 0.f;
#pragma unroll
  for (int z = 0; z < DH; ++z) {
    qt += ra[z] * qs[h * DH + z];
    mt += rm[z * DH] * vs[h * DH + z];
  }
  qt *= rp[h] * 0.25f;  // rel_pri * 1/sqrt(Dh)
  oqt[(size_t)n * D + j] = qt;
  omt[(size_t)n * D + j] = mt;
}

// ---------- edge pass 1: a = dot16(k[src,h], qt[dst,h]); atomicMax amax ----------
__global__ void k_edge1(const int* __restrict__ src, const int* __restrict__ dst,
                        const float* __restrict__ kk, const float* __restrict__ qt,
                        float* __restrict__ a, unsigned int* __restrict__ amax, int E) {
  int t = blockIdx.x * blockDim.x + threadIdx.x;
  if (t >= E * H) return;
  int e = t >> 3, h = t & 7;
  int s = src[e], dn = dst[e];
  const float4* kp = (const float4*)(kk + (size_t)s * D + h * DH);
  const float4* qp = (const float4*)(qt + (size_t)dn * D + h * DH);
  float acc = 0.f;
#pragma unroll
  for (int z = 0; z < 4; ++z) {
    float4 kv = kp[z], qv = qp[z];
    acc += kv.x * qv.x + kv.y * qv.y + kv.z * qv.z + kv.w * qv.w;
  }
  a[t] = acc;
  atomicMax(amax + (size_t)dn * H + h, fkey(acc));
}

// ---------- edge pass 2: ae = exp(a - amax[dst]); atomicAdd asum ----------
__global__ void k_edge2(const int* __restrict__ dst, float* __restrict__ a,
                        const unsigned int* __restrict__ amax, float* __restrict__ asum,
                        int E) {
  int t = blockIdx.x * blockDim.x + threadIdx.x;
  if (t >= E * H) return;
  int e = t >> 3, h = t & 7;
  int dn = dst[e];
  float mx = fdec(amax[(size_t)dn * H + h]);
  float ae = __expf(a[t] - mx);
  a[t] = ae;
  atomicAdd(asum + (size_t)dn * H + h, ae);
}

// ---------- edge pass 3: h_agg[dst] += (ae/asum[dst]) * mt[src] ----------
__global__ void k_edge3(const int* __restrict__ src, const int* __restrict__ dst,
                        const float* __restrict__ mt, const float* __restrict__ a,
                        const float* __restrict__ asum, float* __restrict__ hagg, int E) {
  int t = blockIdx.x * blockDim.x + threadIdx.x;
  if (t >= E * H) return;
  int e = t >> 3, h = t & 7;
  int s = src[e], dn = dst[e];
  float attn = a[t] / asum[(size_t)dn * H + h];
  const float4* mp = (const float4*)(mt + (size_t)s * D + h * DH);
  float* hp = hagg + (size_t)dn * D + h * DH;
#pragma unroll
  for (int z = 0; z < 4; ++z) {
    float4 mv = mp[z];
    atomicAdd(hp + z * 4 + 0, attn * mv.x);
    atomicAdd(hp + z * 4 + 1, attn * mv.y);
    atomicAdd(hp + z * 4 + 2, attn * mv.z);
    atomicAdd(hp + z * 4 + 3, attn * mv.w);
  }
}

// ---------- final: h = h_agg@Wa[t]; skip-mix; LayerNorm; +x; FiLM ----------
__global__ void k_final(const float* __restrict__ x, const int* __restrict__ ntype,
                        const float* __restrict__ Wa, const float* __restrict__ skip,
                        const float* __restrict__ ln_g, const float* __restrict__ ln_b,
                        const float* __restrict__ gb, const float* __restrict__ hagg,
                        float* __restrict__ out, int N) {
  int n = blockIdx.x;
  int j = threadIdx.x;  // 0..127
  __shared__ float hs[D];
  __shared__ float ps1[2], ps2[2];
  hs[j] = hagg[(size_t)n * D + j];
  __syncthreads();
  int t = ntype[n];
  const float* wp = Wa + (size_t)t * (D * D) + j;
  float acc = 0.f;
#pragma unroll 8
  for (int d = 0; d < D; ++d) acc += hs[d] * wp[d * D];
  float alpha = 1.f / (1.f + __expf(-skip[t]));
  float xv = x[(size_t)n * D + j];
  float h = acc * alpha + xv * (1.f - alpha);
  float s1 = h, s2 = h * h;
#pragma unroll
  for (int o = 1; o < 64; o <<= 1) {
    s1 += __shfl_xor(s1, o);
    s2 += __shfl_xor(s2, o);
  }
  if ((j & 63) == 0) { ps1[j >> 6] = s1; ps2[j >> 6] = s2; }
  __syncthreads();
  float mu = (ps1[0] + ps1[1]) * (1.f / D);
  float m2 = (ps2[0] + ps2[1]) * (1.f / D);
  float var = m2 - mu * mu;
  float y = (h - mu) * rsqrtf(var + 1e-5f) * ln_g[j] + ln_b[j];
  y += xv;
  out[(size_t)n * D + j] = gb[j] * y + gb[D + j];
}

extern "C" void kernel_launch(void* const* d_in, const int* in_sizes, int n_in,
                              void* d_out, int out_size, void* d_ws, size_t ws_size,
                              hipStream_t stream) {
  const float* x       = (const float*)d_in[0];
  const float* gc      = (const float*)d_in[1];
  const float* Wk      = (const float*)d_in[2];
  const float* Wq      = (const float*)d_in[3];
  const float* Wv      = (const float*)d_in[4];
  const float* rel_att = (const float*)d_in[5];
  const float* rel_msg = (const float*)d_in[6];
  const float* rel_pri = (const float*)d_in[7];
  const float* Wa      = (const float*)d_in[8];
  const float* skip    = (const float*)d_in[9];
  const float* ln_g    = (const float*)d_in[10];
  const float* ln_b    = (const float*)d_in[11];
  const float* fw      = (const float*)d_in[12];
  const float* fb      = (const float*)d_in[13];
  const int* ntype     = (const int*)d_in[14];
  const int* src       = (const int*)d_in[15];
  const int* dst       = (const int*)d_in[16];
  float* out = (float*)d_out;

  int N = in_sizes[0] / D;
  int C = in_sizes[1];
  int E = in_sizes[15];

  float* ws = (float*)d_ws;
  size_t nD = (size_t)N * D;
  float* wk_   = ws;             // N*128   k
  float* wqt   = wk_ + nD;       // N*128   qt (scaled)
  float* wmt   = wqt + nD;       // N*128   mt
  float* wa    = wmt + nD;       // E*8     a -> ae
  unsigned int* wamax = (unsigned int*)(wa + (size_t)E * H);  // N*8
  float* wasum = (float*)(wamax + (size_t)N * H);             // N*8
  float* whagg = wasum + (size_t)N * H;                       // N*128
  float* wgb   = whagg + nD;                                  // 256

  k_film<<<1, 2 * D, 0, stream>>>(gc, fw, fb, wgb, C);
  k_init<<<(N * D + 255) / 256, 256, 0, stream>>>(whagg, wasum, wamax, N);
  k_proj<<<N, D, 0, stream>>>(x, ntype, Wk, Wq, Wv, rel_att, rel_msg, rel_pri,
                              wk_, wqt, wmt, N);
  int tE = E * H;
  k_edge1<<<(tE + 255) / 256, 256, 0, stream>>>(src, dst, wk_, wqt, wa, wamax, E);
  k_edge2<<<(tE + 255) / 256, 256, 0, stream>>>(dst, wa, wamax, wasum, E);
  k_edge3<<<(tE + 255) / 256, 256, 0, stream>>>(src, dst, wmt, wa, wasum, whagg, E);
  k_final<<<N, D, 0, stream>>>(x, ntype, Wa, skip, ln_g, ln_b, wgb, whagg, out, N);
}

// Round 2
// 313.155 us; speedup vs baseline: 8.2274x; 8.2274x over previous
//
#include <hip/hip_runtime.h>
#include <hip/hip_bf16.h>

constexpr int D  = 128;
constexpr int H  = 8;
constexpr int DH = 16;

// ---------- FiLM: gb[0:128]=gamma, gb[128:256]=beta ----------
__global__ void k_film(const float* __restrict__ gc, const float* __restrict__ fw,
                       const float* __restrict__ fb, float* __restrict__ gb, int C) {
  int j = threadIdx.x;  // 256 threads
  float acc = fb[j];
  for (int c = 0; c < C; ++c) acc += gc[c] * fw[c * 256 + j];
  gb[j] = acc;
}

// ---------- zero deg + cursor ----------
__global__ void k_zero(int* __restrict__ deg, int* __restrict__ cursor, int N) {
  int i = blockIdx.x * blockDim.x + threadIdx.x;
  if (i < N) { deg[i] = 0; cursor[i] = 0; }
}

// ---------- count in-degree ----------
__global__ void k_count(const int* __restrict__ dst, int* __restrict__ deg, int E) {
  int e = blockIdx.x * blockDim.x + threadIdx.x;
  if (e < E) atomicAdd(deg + dst[e], 1);
}

// ---------- exclusive prefix sum over deg[0..N-1] -> off[0..N], single block 1024 ----------
__global__ void k_scan(const int* __restrict__ deg, int* __restrict__ off, int N, int E) {
  __shared__ int wsum[16];
  __shared__ int base_s;
  int tid = threadIdx.x;          // 0..1023
  int lane = tid & 63, w = tid >> 6;
  if (tid == 0) base_s = 0;
  __syncthreads();
  for (int start = 0; start < N; start += 1024) {
    int i = start + tid;
    int v = (i < N) ? deg[i] : 0;
    int x = v;  // inclusive scan within wave
#pragma unroll
    for (int o = 1; o < 64; o <<= 1) {
      int y = __shfl_up(x, o);
      if (lane >= o) x += y;
    }
    if (lane == 63) wsum[w] = x;
    __syncthreads();
    if (w == 0 && lane < 16) {
      int s = wsum[lane];
#pragma unroll
      for (int o = 1; o < 16; o <<= 1) {
        int y = __shfl_up(s, o);
        if (lane >= o) s += y;
      }
      wsum[lane] = s;
    }
    __syncthreads();
    int waveoff = (w > 0) ? wsum[w - 1] : 0;
    if (i < N) off[i] = base_s + waveoff + x - v;
    __syncthreads();
    if (tid == 0) base_s += wsum[15];
    __syncthreads();
  }
  if (tid == 0) off[N] = E;
}

// ---------- scatter edge ids into CSR buckets ----------
__global__ void k_scatter(const int* __restrict__ dst, const int* __restrict__ off,
                          int* __restrict__ cursor, int* __restrict__ eid, int E) {
  int e = blockIdx.x * blockDim.x + threadIdx.x;
  if (e >= E) return;
  int d = dst[e];
  int pos = atomicAdd(cursor + d, 1);
  eid[off[d] + pos] = e;
}

// ---------- per-node: k = x@Wk[t]; q = x@Wq[t]; v = x@Wv[t];
//            qt[h,d] = (rel_pri[h]/4) * sum_o rel_att[h,d,o]*q[h,o]
//            mt[h,o] = sum_d rel_msg[h,d,o]*v[h,d] ----------
__global__ void k_proj(const float* __restrict__ x, const int* __restrict__ ntype,
                       const float* __restrict__ Wk, const float* __restrict__ Wq,
                       const float* __restrict__ Wv, const float* __restrict__ ra_,
                       const float* __restrict__ rm_, const float* __restrict__ rp,
                       float* __restrict__ ok, float* __restrict__ oqt,
                       float* __restrict__ omt, int N) {
  int n = blockIdx.x;
  int j = threadIdx.x;  // 0..127
  __shared__ float xs[D], qs[D], vs[D];
  xs[j] = x[(size_t)n * D + j];
  __syncthreads();
  int t = ntype[n];
  const float* wk = Wk + (size_t)t * (D * D) + j;
  const float* wq = Wq + (size_t)t * (D * D) + j;
  const float* wv = Wv + (size_t)t * (D * D) + j;
  float ak = 0.f, aq = 0.f, av = 0.f;
#pragma unroll 8
  for (int d = 0; d < D; ++d) {
    float xv = xs[d];
    ak += xv * wk[d * D];
    aq += xv * wq[d * D];
    av += xv * wv[d * D];
  }
  ok[(size_t)n * D + j] = ak;
  qs[j] = aq;
  vs[j] = av;
  __syncthreads();
  int h = j >> 4, o = j & 15;
  const float* ra = ra_ + h * 256 + o * 16;  // rel_att[h, d=o, z]
  const float* rm = rm_ + h * 256 + o;       // rel_msg[h, z, o=o]
  float qt = 0.f, mt = 0.f;
#pragma unroll
  for (int z = 0; z < DH; ++z) {
    qt += ra[z] * qs[h * DH + z];
    mt += rm[z * DH] * vs[h * DH + z];
  }
  qt *= rp[h] * 0.25f;  // rel_pri * 1/sqrt(Dh)
  oqt[(size_t)n * D + j] = qt;
  omt[(size_t)n * D + j] = mt;
}

// ---------- fused: per-node online-softmax aggregation over CSR edge list,
//            then h = h_agg@Wa[t]; skip-mix; LayerNorm; +x; FiLM ----------
__global__ void k_agg(const int* __restrict__ eid, const int* __restrict__ off,
                      const int* __restrict__ src,
                      const float* __restrict__ kk, const float* __restrict__ qt,
                      const float* __restrict__ mt,
                      const float* __restrict__ x, const int* __restrict__ ntype,
                      const float* __restrict__ Wa, const float* __restrict__ skip,
                      const float* __restrict__ ln_g, const float* __restrict__ ln_b,
                      const float* __restrict__ gb,
                      float* __restrict__ out, int N) {
  int n = blockIdx.x;
  int j = threadIdx.x;  // 0..127
  float qv = qt[(size_t)n * D + j];
  int i0 = off[n], i1 = off[n + 1];
  float m = -INFINITY, ssum = 0.f, acc = 0.f;
  for (int i = i0; i < i1; ++i) {
    int e = eid[i];
    int sn = src[e];
    float kv = kk[(size_t)sn * D + j];
    float mv = mt[(size_t)sn * D + j];
    float p = kv * qv;  // reduce over the 16 lanes of this head group
    p += __shfl_xor(p, 8);
    p += __shfl_xor(p, 4);
    p += __shfl_xor(p, 2);
    p += __shfl_xor(p, 1);
    float mn = fmaxf(m, p);
    float sc = __expf(m - mn);   // first iter: exp(-inf)=0
    float wgt = __expf(p - mn);
    ssum = ssum * sc + wgt;
    acc = acc * sc + wgt * mv;
    m = mn;
  }
  float hval = (ssum > 0.f) ? acc / ssum : 0.f;

  __shared__ float hs[D];
  __shared__ float ps1[2], ps2[2];
  hs[j] = hval;
  __syncthreads();
  int t = ntype[n];
  const float* wp = Wa + (size_t)t * (D * D) + j;
  float acc2 = 0.f;
#pragma unroll 8
  for (int d = 0; d < D; ++d) acc2 += hs[d] * wp[d * D];
  float alpha = 1.f / (1.f + __expf(-skip[t]));
  float xv = x[(size_t)n * D + j];
  float h = acc2 * alpha + xv * (1.f - alpha);
  float s1 = h, s2 = h * h;
#pragma unroll
  for (int o = 1; o < 64; o <<= 1) {
    s1 += __shfl_xor(s1, o);
    s2 += __shfl_xor(s2, o);
  }
  if ((j & 63) == 0) { ps1[j >> 6] = s1; ps2[j >> 6] = s2; }
  __syncthreads();
  float mu = (ps1[0] + ps1[1]) * (1.f / D);
  float m2 = (ps2[0] + ps2[1]) * (1.f / D);
  float var = m2 - mu * mu;
  float y = (h - mu) * rsqrtf(var + 1e-5f) * ln_g[j] + ln_b[j];
  y += xv;
  out[(size_t)n * D + j] = gb[j] * y + gb[D + j];
}

extern "C" void kernel_launch(void* const* d_in, const int* in_sizes, int n_in,
                              void* d_out, int out_size, void* d_ws, size_t ws_size,
                              hipStream_t stream) {
  const float* x       = (const float*)d_in[0];
  const float* gc      = (const float*)d_in[1];
  const float* Wk      = (const float*)d_in[2];
  const float* Wq      = (const float*)d_in[3];
  const float* Wv      = (const float*)d_in[4];
  const float* rel_att = (const float*)d_in[5];
  const float* rel_msg = (const float*)d_in[6];
  const float* rel_pri = (const float*)d_in[7];
  const float* Wa      = (const float*)d_in[8];
  const float* skip    = (const float*)d_in[9];
  const float* ln_g    = (const float*)d_in[10];
  const float* ln_b    = (const float*)d_in[11];
  const float* fw      = (const float*)d_in[12];
  const float* fb      = (const float*)d_in[13];
  const int* ntype     = (const int*)d_in[14];
  const int* src       = (const int*)d_in[15];
  const int* dst       = (const int*)d_in[16];
  float* out = (float*)d_out;

  int N = in_sizes[0] / D;
  int C = in_sizes[1];
  int E = in_sizes[15];

  float* ws = (float*)d_ws;
  size_t nD = (size_t)N * D;
  float* wk_  = ws;              // N*128   k
  float* wqt  = wk_ + nD;        // N*128   qt (scaled)
  float* wmt  = wqt + nD;        // N*128   mt
  float* wgb  = wmt + nD;        // 256     gamma|beta
  int*   deg    = (int*)(wgb + 256);  // N
  int*   off    = deg + N;            // N+1
  int*   cursor = off + N + 1;        // N
  int*   eid    = cursor + N;         // E

  k_film<<<1, 2 * D, 0, stream>>>(gc, fw, fb, wgb, C);
  k_zero<<<(N + 255) / 256, 256, 0, stream>>>(deg, cursor, N);
  k_count<<<(E + 255) / 256, 256, 0, stream>>>(dst, deg, E);
  k_scan<<<1, 1024, 0, stream>>>(deg, off, N, E);
  k_scatter<<<(E + 255) / 256, 256, 0, stream>>>(dst, off, cursor, eid, E);
  k_proj<<<N, D, 0, stream>>>(x, ntype, Wk, Wq, Wv, rel_att, rel_msg, rel_pri,
                              wk_, wqt, wmt, N);
  k_agg<<<N, D, 0, stream>>>(eid, off, src, wk_, wqt, wmt, x, ntype, Wa, skip,
                             ln_g, ln_b, wgb, out, N);
}